// Round 1
// 725.896 us; speedup vs baseline: 1.0085x; 1.0085x over previous
//
#include <hip/hip_runtime.h>

#define MINV 1e-15f
#define MAXNRM 0.996f   // (1 - PROJ_EPS)/sqrt(c), c=1, PROJ_EPS=0.004

// butterfly sum over 64 lanes; every lane ends with the total
__device__ __forceinline__ float wsum(float v) {
#pragma unroll
    for (int m = 32; m; m >>= 1) v += __shfl_xor(v, m, 64);
    return v;
}

__device__ __forceinline__ float artanhf_(float x) {
    x = fminf(fmaxf(x, -1.0f + 1e-7f), 1.0f - 1e-7f);
    return 0.5f * logf((1.0f + x) / (1.0f - x));
}

// dot-4 of a float4 row chunk against 4 shuffled-broadcast components of v
#define MATVEC4(q, d0, v, acc)                                              \
    acc += (q).x * __shfl((v), (d0) + 0, 64)                                \
         + (q).y * __shfl((v), (d0) + 1, 64)                                \
         + (q).z * __shfl((v), (d0) + 2, 64)                                \
         + (q).w * __shfl((v), (d0) + 3, 64);

// ============================================================================
// Kernel 1: stream Wr (512 MB) once; write raw bilinear logits to scratch.
// Low VGPR -> high occupancy -> HBM-bound. Inner loop: 1 VMEM + 1 ds_read +
// 4 FMA per 16B (t_self dot hoisted out of the j-loop via float4 accumulator).
// ============================================================================
__global__ __launch_bounds__(256) void logits_kernel(
    const float* __restrict__ self_v,   // (B,1,64)
    const float* __restrict__ ent_v,    // (B,1,16,64)
    const float* __restrict__ Wr,       // (B,1,16,64,64)
    float* __restrict__ scratch)        // raw logit s at [b*64+s] (reuses out)
{
    __shared__ float sE[1024];
    __shared__ float st[64];
    const int b = blockIdx.x, tid = threadIdx.x, lane = tid & 63, wv = tid >> 6;

    for (int i = tid; i < 1024; i += 256)
        sE[i] = ent_v[(size_t)b * 1024 + i];
    if (wv == 0) {
        float xl = self_v[(size_t)b * 64 + lane];
        float x2 = wsum(xl * xl);
        float xn = fmaxf(sqrtf(x2), MINV);
        st[lane] = artanhf_(xn) / xn * xl;
    }
    __syncthreads();

    const float4* wp = (const float4*)(Wr + (size_t)b * 65536);
    const int r0 = lane >> 4;            // row offset within the j-quad
    const int c0 = (lane & 15) * 4;      // col chunk start
    const float t0 = st[c0], t1 = st[c0 + 1], t2 = st[c0 + 2], t3 = st[c0 + 3];

    for (int s = wv; s < 16; s += 4) {
        const float4* sp = wp + s * 1024;   // 4096 floats per s
        float ax = 0.f, ay = 0.f, az = 0.f, aw = 0.f;
#pragma unroll
        for (int j = 0; j < 16; ++j) {
            float4 q = sp[j * 64 + lane];           // contiguous 1KB per wave
            float er = sE[s * 64 + j * 4 + r0];     // raw E (t_e scale applied in k2)
            ax += q.x * er; ay += q.y * er; az += q.z * er; aw += q.w * er;
        }
        float dp = wsum(ax * t0 + ay * t1 + az * t2 + aw * t3);
        if (lane == 0) scratch[(size_t)b * 64 + s] = dp;
    }
}

// ============================================================================
// Kernel 2: everything else. The two 16-s logmap loops are parallelized
// across 4 waves (4 s each, unrolled -> ~20 independent shuffle chains);
// per-s direction vectors staged in LDS; wave 0 does the short combine.
// ============================================================================
__global__ __launch_bounds__(256) void tail_kernel(
    const float* __restrict__ self_v,   // (B,1,64)
    const float* __restrict__ user_v,   // (B,16,64)
    const float* __restrict__ ent_v,    // (B,1,16,64)
    const float* __restrict__ item_e,   // (B,64)
    const float* __restrict__ Wui,      // (64,64)
    const float* __restrict__ linW,     // (64,64)
    const float* __restrict__ linb,     // (64,)
    float* __restrict__ out)            // raw logits in cols 0..15; final (B,1,64)
{
    __shared__ float sE[1024], sU[1024];
    __shared__ float sSub[16][64];      // KG:  artanh(sn)/sn * sub
    __shared__ float sUSub[16][64];     // user: same
    __shared__ float sLog[16], sULog[16];
    __shared__ float sImw[64];          // Wui @ t_item
    __shared__ float sHb[64];           // proj(expmap0(linb))
    __shared__ float sH2;

    const int b = blockIdx.x, tid = threadIdx.x, lane = tid & 63, wv = tid >> 6;

    for (int i = tid; i < 1024; i += 256) {
        sE[i] = ent_v[(size_t)b * 1024 + i];
        sU[i] = user_v[(size_t)b * 1024 + i];
    }

    // every wave computes its own self/item stats (cheap, avoids extra barrier)
    const float xl = self_v[(size_t)b * 64 + lane];
    const float x2 = wsum(xl * xl);
    const float ivl = item_e[(size_t)b * 64 + lane];
    const float i2 = wsum(ivl * ivl);

    if (wv == 3) {
        // imW = Wui @ t_item  (off the critical chain)
        float inn = fmaxf(sqrtf(i2), MINV);
        float til = artanhf_(inn) / inn * ivl;
        float imw = 0.f;
        const float4* wq = (const float4*)Wui;
#pragma unroll
        for (int j = 0; j < 16; ++j) {
            float4 q = wq[lane * 16 + j];
            MATVEC4(q, j * 4, til, imw)
        }
        sImw[lane] = imw;
    } else if (wv == 2) {
        // hb = proj(expmap0(linb))  (off the critical chain)
        float bl = linb[lane];
        float bn = fmaxf(sqrtf(wsum(bl * bl)), MINV);
        float hb = tanhf(bn) * bl / bn;
        float hn = fmaxf(sqrtf(wsum(hb * hb)), MINV);
        if (hn > MAXNRM) hb = hb / hn * MAXNRM;
        sHb[lane] = hb;
        float h2 = wsum(hb * hb);
        if (lane == 0) sH2 = h2;
    }
    __syncthreads();

    // ---- phase 1: per-s logmap directions + logits, 4 s per wave ----
    {
        const float imw = sImw[lane];
        const float omx2 = 1.f - x2;
        const float omi2 = 1.f - i2;
#pragma unroll
        for (int q = 0; q < 4; ++q) {
            const int s = wv * 4 + q;
            float el = sE[s * 64 + lane];
            float ul = sU[s * 64 + lane];
            // five independent reductions -> pipelined shuffle chains
            float e2  = wsum(el * el);
            float dxe = wsum(xl * el);
            float u2  = wsum(ul * ul);
            float dxy = wsum(ivl * ul);
            float ur  = wsum(imw * ul);

            float en = fmaxf(sqrtf(e2), MINV);
            if (lane == 0)
                sLog[s] = artanhf_(en) / en * out[(size_t)b * 64 + s];
            float den  = fmaxf(1.f - 2.f * dxe + x2 * e2, MINV);
            float subl = ((1.f - 2.f * dxe + e2) * (-xl) + omx2 * el) / den;

            float unr = fmaxf(sqrtf(u2), MINV);
            if (lane == 0)
                sULog[s] = artanhf_(unr) / unr * ur;
            float uden = fmaxf(1.f - 2.f * dxy + i2 * u2, MINV);
            float usub = ((1.f - 2.f * dxy + u2) * (-ivl) + omi2 * ul) / uden;

            float sn  = fmaxf(sqrtf(wsum(subl * subl)), MINV);
            float usn = fmaxf(sqrtf(wsum(usub * usub)), MINV);
            sSub[s][lane]  = artanhf_(sn) / sn * subl;
            sUSub[s][lane] = artanhf_(usn) / usn * usub;
        }
    }
    __syncthreads();
    if (wv != 0) return;   // waves 1-3 done; no more barriers below

    // ---- phase 2 (wave 0): softmax + aggregate + expmap, both branches ----
    float mx = -1e30f, umx = -1e30f;
#pragma unroll
    for (int s = 0; s < 16; ++s) {
        mx = fmaxf(mx, sLog[s]);
        umx = fmaxf(umx, sULog[s]);
    }
    float se = 0.f, usum = 0.f, aggl = 0.f, uaggl = 0.f;
#pragma unroll
    for (int s = 0; s < 16; ++s) {
        float e = expf(sLog[s] - mx);
        se += e; aggl += e * sSub[s][lane];
        float ue = expf(sULog[s] - umx);
        usum += ue; uaggl += ue * sUSub[s][lane];
    }
    float lam  = fmaxf(2.f / (1.f - x2), MINV);
    float lami = fmaxf(2.f / (1.f - i2), MINV);
    aggl  *= (2.f / lam) / se;     // fold (2/lam) * att-normalization
    uaggl *= (2.f / lami) / usum;

    // two independent expmap chains interleave for ILP
    float un  = fmaxf(sqrtf(wsum(aggl * aggl)), MINV);
    float uun = fmaxf(sqrtf(wsum(uaggl * uaggl)), MINV);
    float secl = tanhf(lam * un * 0.5f) * aggl / un;
    float usec = tanhf(lami * uun * 0.5f) * uaggl / uun;

    float ss2 = wsum(secl * secl), xss = wsum(xl * secl);
    float us2 = wsum(usec * usec), uxs = wsum(ivl * usec);
    float kgl = ((1.f + 2.f * xss + ss2) * xl + (1.f - x2) * secl)
              / fmaxf(1.f + 2.f * xss + x2 * ss2, MINV);
    float ual = ((1.f + 2.f * uxs + us2) * ivl + (1.f - i2) * usec)
              / fmaxf(1.f + 2.f * uxs + i2 * us2, MINV);

    // ---- combine: mobius_add(mobius_add(x, kg), user) ----
    float k2 = wsum(kgl * kgl), xk = wsum(xl * kgl);
    float o1 = ((1.f + 2.f * xk + k2) * xl + (1.f - x2) * kgl)
             / fmaxf(1.f + 2.f * xk + x2 * k2, MINV);
    float o12 = wsum(o1 * o1), ua2 = wsum(ual * ual), o1u = wsum(o1 * ual);
    float v   = ((1.f + 2.f * o1u + ua2) * o1 + (1.f - o12) * ual)
              / fmaxf(1.f + 2.f * o1u + o12 * ua2, MINV);

    // ---- hyp_linear ----
    float v2 = wsum(v * v);
    float vn = fmaxf(sqrtf(v2), MINV);
    float mxv = 0.f;
    {
        const float4* wq = (const float4*)linW;
#pragma unroll
        for (int j = 0; j < 16; ++j) {
            float4 q = wq[lane * 16 + j];
            MATVEC4(q, j * 4, v, mxv)
        }
    }
    float mxn = fmaxf(sqrtf(wsum(mxv * mxv)), MINV);
    float res = tanhf(mxn / vn * artanhf_(vn)) * mxv / mxn;
    if (__ballot(mxv != 0.f) == 0ull) res = 0.f;   // all(mx==0) guard
    float rn = fmaxf(sqrtf(wsum(res * res)), MINV);
    if (rn > MAXNRM) res = res / rn * MAXNRM;

    float hb = sHb[lane];
    float h2 = sH2;
    float r2 = wsum(res * res), rh = wsum(res * hb);
    float o3 = ((1.f + 2.f * rh + h2) * res + (1.f - r2) * hb)
             / fmaxf(1.f + 2.f * rh + r2 * h2, MINV);
    float on = fmaxf(sqrtf(wsum(o3 * o3)), MINV);
    if (on > MAXNRM) o3 = o3 / on * MAXNRM;

    // ---- final: expmap0(tanh(logmap0(o3))) ----
    float on2 = fmaxf(sqrtf(wsum(o3 * o3)), MINV);
    float tl  = tanhf(artanhf_(on2) / on2 * o3);
    float tn  = fmaxf(sqrtf(wsum(tl * tl)), MINV);
    out[(size_t)b * 64 + lane] = tanhf(tn) * tl / tn;
}

extern "C" void kernel_launch(void* const* d_in, const int* in_sizes, int n_in,
                              void* d_out, int out_size, void* d_ws, size_t ws_size,
                              hipStream_t stream) {
    const float* self_v = (const float*)d_in[0];
    const float* user_v = (const float*)d_in[1];
    const float* ent_v  = (const float*)d_in[2];
    const float* item_e = (const float*)d_in[3];
    const float* Wr     = (const float*)d_in[4];
    const float* Wui    = (const float*)d_in[5];
    const float* linW   = (const float*)d_in[6];
    const float* linb   = (const float*)d_in[7];
    float* out = (float*)d_out;

    const int B = in_sizes[0] / 64;   // 2048

    // Kernel 1 parks raw logits in out[b*64 + s] (s<16); kernel 2 consumes
    // them and then overwrites the full row. No workspace needed.
    logits_kernel<<<B, 256, 0, stream>>>(self_v, ent_v, Wr, out);
    tail_kernel<<<B, 256, 0, stream>>>(self_v, user_v, ent_v, item_e,
                                       Wui, linW, linb, out);
}

// Round 2
// 724.139 us; speedup vs baseline: 1.0109x; 1.0024x over previous
//
#include <hip/hip_runtime.h>

#define MINV 1e-15f
#define MAXNRM 0.996f   // (1 - PROJ_EPS)/sqrt(c), c=1, PROJ_EPS=0.004

// butterfly sum over 64 lanes; every lane ends with the total
__device__ __forceinline__ float wsum(float v) {
#pragma unroll
    for (int m = 32; m; m >>= 1) v += __shfl_xor(v, m, 64);
    return v;
}

__device__ __forceinline__ float artanhf_(float x) {
    x = fminf(fmaxf(x, -1.0f + 1e-7f), 1.0f - 1e-7f);
    return 0.5f * logf((1.0f + x) / (1.0f - x));
}

// dot-4 of a float4 row chunk against 4 shuffled-broadcast components of v
#define MATVEC4(q, d0, v, acc)                                              \
    acc += (q).x * __shfl((v), (d0) + 0, 64)                                \
         + (q).y * __shfl((v), (d0) + 1, 64)                                \
         + (q).z * __shfl((v), (d0) + 2, 64)                                \
         + (q).w * __shfl((v), (d0) + 3, 64);

// ============================================================================
// Kernel 1: one block per (b,s) 16KB tile of Wr. 4 float4 loads/thread issued
// before the staging barrier; 16 FMAs/thread; one wave-reduce + LDS combine.
// Writes the SCALED logit (artanh(|E|)/|E| folded in). Copy-kernel streaming
// shape: no rolled loop, no per-burst drain, ~40 VGPR -> max occupancy.
// ============================================================================
__global__ __launch_bounds__(256) void logits_kernel(
    const float* __restrict__ self_v,   // (B,1,64)
    const float* __restrict__ ent_v,    // (B,1,16,64)
    const float* __restrict__ Wr,       // (B,1,16,64,64)
    float* __restrict__ scratch)        // scaled logit at [b*64+s] (reuses out)
{
    __shared__ float sEr[64];   // E row for this (b,s)
    __shared__ float sT[64];    // t_self = logmap0(self)
    __shared__ float sRed[4];
    __shared__ float sScale;

    const int blk = blockIdx.x, b = blk >> 4, s = blk & 15;
    const int t = threadIdx.x, lane = t & 63, wv = t >> 6;

    // ---- issue the 16KB tile loads first (fly during staging) ----
    const float4* wp = (const float4*)(Wr + (size_t)b * 65536 + (size_t)s * 4096);
    float4 q0 = wp[t];
    float4 q1 = wp[t + 256];
    float4 q2 = wp[t + 512];
    float4 q3 = wp[t + 768];

    if (wv == 0) {
        float el = ent_v[(size_t)b * 1024 + s * 64 + lane];
        sEr[lane] = el;
        float en = fmaxf(sqrtf(wsum(el * el)), MINV);
        if (lane == 0) sScale = artanhf_(en) / en;
    } else if (wv == 1) {
        float xl = self_v[(size_t)b * 64 + lane];
        float xn = fmaxf(sqrtf(wsum(xl * xl)), MINV);
        sT[lane] = artanhf_(xn) / xn * xl;
    }
    __syncthreads();

    // thread t covers rows r0+16k (k=0..3), cols c0..c0+3 (c0 = (t&15)*4)
    const float4 ts = ((const float4*)sT)[t & 15];
    const int r0 = t >> 4;
    float p = sEr[r0]      * (q0.x * ts.x + q0.y * ts.y + q0.z * ts.z + q0.w * ts.w)
            + sEr[r0 + 16] * (q1.x * ts.x + q1.y * ts.y + q1.z * ts.z + q1.w * ts.w)
            + sEr[r0 + 32] * (q2.x * ts.x + q2.y * ts.y + q2.z * ts.z + q2.w * ts.w)
            + sEr[r0 + 48] * (q3.x * ts.x + q3.y * ts.y + q3.z * ts.z + q3.w * ts.w);
    p = wsum(p);
    if (lane == 0) sRed[wv] = p;
    __syncthreads();
    if (t == 0)
        scratch[(size_t)b * 64 + s] =
            sScale * (sRed[0] + sRed[1] + sRed[2] + sRed[3]);
}

// ============================================================================
// Kernel 2: everything else. Two 16-s logmap loops parallelized across 4
// waves (4 s each); per-s direction vectors staged in LDS; wave 0 does the
// short combine. Logits arrive pre-scaled from kernel 1.
// ============================================================================
__global__ __launch_bounds__(256) void tail_kernel(
    const float* __restrict__ self_v,   // (B,1,64)
    const float* __restrict__ user_v,   // (B,16,64)
    const float* __restrict__ ent_v,    // (B,1,16,64)
    const float* __restrict__ item_e,   // (B,64)
    const float* __restrict__ Wui,      // (64,64)
    const float* __restrict__ linW,     // (64,64)
    const float* __restrict__ linb,     // (64,)
    float* __restrict__ out)            // scaled logits in cols 0..15; final (B,1,64)
{
    __shared__ float sE[1024], sU[1024];
    __shared__ float sSub[16][64];      // KG:  artanh(sn)/sn * sub
    __shared__ float sUSub[16][64];     // user: same
    __shared__ float sLog[16], sULog[16];
    __shared__ float sImw[64];          // Wui @ t_item
    __shared__ float sHb[64];           // proj(expmap0(linb))
    __shared__ float sH2;

    const int b = blockIdx.x, tid = threadIdx.x, lane = tid & 63, wv = tid >> 6;

    for (int i = tid; i < 1024; i += 256) {
        sE[i] = ent_v[(size_t)b * 1024 + i];
        sU[i] = user_v[(size_t)b * 1024 + i];
    }
    if (tid < 16) sLog[tid] = out[(size_t)b * 64 + tid];  // scaled KG logits

    // every wave computes its own self/item stats (cheap, avoids extra barrier)
    const float xl = self_v[(size_t)b * 64 + lane];
    const float x2 = wsum(xl * xl);
    const float ivl = item_e[(size_t)b * 64 + lane];
    const float i2 = wsum(ivl * ivl);

    if (wv == 3) {
        // imW = Wui @ t_item  (off the critical chain)
        float inn = fmaxf(sqrtf(i2), MINV);
        float til = artanhf_(inn) / inn * ivl;
        float imw = 0.f;
        const float4* wq = (const float4*)Wui;
#pragma unroll
        for (int j = 0; j < 16; ++j) {
            float4 q = wq[lane * 16 + j];
            MATVEC4(q, j * 4, til, imw)
        }
        sImw[lane] = imw;
    } else if (wv == 2) {
        // hb = proj(expmap0(linb))  (off the critical chain)
        float bl = linb[lane];
        float bn = fmaxf(sqrtf(wsum(bl * bl)), MINV);
        float hb = tanhf(bn) * bl / bn;
        float hn = fmaxf(sqrtf(wsum(hb * hb)), MINV);
        if (hn > MAXNRM) hb = hb / hn * MAXNRM;
        sHb[lane] = hb;
        float h2 = wsum(hb * hb);
        if (lane == 0) sH2 = h2;
    }
    __syncthreads();

    // ---- phase 1: per-s logmap directions + user logits, 4 s per wave ----
    {
        const float imw = sImw[lane];
        const float omx2 = 1.f - x2;
        const float omi2 = 1.f - i2;
#pragma unroll
        for (int q = 0; q < 4; ++q) {
            const int s = wv * 4 + q;
            float el = sE[s * 64 + lane];
            float ul = sU[s * 64 + lane];
            // four independent reductions -> pipelined shuffle chains
            float dxe = wsum(xl * el);
            float u2  = wsum(ul * ul);
            float dxy = wsum(ivl * ul);
            float ur  = wsum(imw * ul);
            float e2  = wsum(el * el);

            float den  = fmaxf(1.f - 2.f * dxe + x2 * e2, MINV);
            float subl = ((1.f - 2.f * dxe + e2) * (-xl) + omx2 * el) / den;

            float unr = fmaxf(sqrtf(u2), MINV);
            if (lane == 0)
                sULog[s] = artanhf_(unr) / unr * ur;
            float uden = fmaxf(1.f - 2.f * dxy + i2 * u2, MINV);
            float usub = ((1.f - 2.f * dxy + u2) * (-ivl) + omi2 * ul) / uden;

            float sn  = fmaxf(sqrtf(wsum(subl * subl)), MINV);
            float usn = fmaxf(sqrtf(wsum(usub * usub)), MINV);
            sSub[s][lane]  = artanhf_(sn) / sn * subl;
            sUSub[s][lane] = artanhf_(usn) / usn * usub;
        }
    }
    __syncthreads();
    if (wv != 0) return;   // waves 1-3 done; no more barriers below

    // ---- phase 2 (wave 0): softmax + aggregate + expmap, both branches ----
    float mx = -1e30f, umx = -1e30f;
#pragma unroll
    for (int s = 0; s < 16; ++s) {
        mx = fmaxf(mx, sLog[s]);
        umx = fmaxf(umx, sULog[s]);
    }
    float se = 0.f, usum = 0.f, aggl = 0.f, uaggl = 0.f;
#pragma unroll
    for (int s = 0; s < 16; ++s) {
        float e = expf(sLog[s] - mx);
        se += e; aggl += e * sSub[s][lane];
        float ue = expf(sULog[s] - umx);
        usum += ue; uaggl += ue * sUSub[s][lane];
    }
    float lam  = fmaxf(2.f / (1.f - x2), MINV);
    float lami = fmaxf(2.f / (1.f - i2), MINV);
    aggl  *= (2.f / lam) / se;     // fold (2/lam) * att-normalization
    uaggl *= (2.f / lami) / usum;

    // two independent expmap chains interleave for ILP
    float un  = fmaxf(sqrtf(wsum(aggl * aggl)), MINV);
    float uun = fmaxf(sqrtf(wsum(uaggl * uaggl)), MINV);
    float secl = tanhf(lam * un * 0.5f) * aggl / un;
    float usec = tanhf(lami * uun * 0.5f) * uaggl / uun;

    float ss2 = wsum(secl * secl), xss = wsum(xl * secl);
    float us2 = wsum(usec * usec), uxs = wsum(ivl * usec);
    float kgl = ((1.f + 2.f * xss + ss2) * xl + (1.f - x2) * secl)
              / fmaxf(1.f + 2.f * xss + x2 * ss2, MINV);
    float ual = ((1.f + 2.f * uxs + us2) * ivl + (1.f - i2) * usec)
              / fmaxf(1.f + 2.f * uxs + i2 * us2, MINV);

    // ---- combine: mobius_add(mobius_add(x, kg), user) ----
    float k2 = wsum(kgl * kgl), xk = wsum(xl * kgl);
    float o1 = ((1.f + 2.f * xk + k2) * xl + (1.f - x2) * kgl)
             / fmaxf(1.f + 2.f * xk + x2 * k2, MINV);
    float o12 = wsum(o1 * o1), ua2 = wsum(ual * ual), o1u = wsum(o1 * ual);
    float v   = ((1.f + 2.f * o1u + ua2) * o1 + (1.f - o12) * ual)
              / fmaxf(1.f + 2.f * o1u + o12 * ua2, MINV);

    // ---- hyp_linear ----
    float v2 = wsum(v * v);
    float vn = fmaxf(sqrtf(v2), MINV);
    float mxv = 0.f;
    {
        const float4* wq = (const float4*)linW;
#pragma unroll
        for (int j = 0; j < 16; ++j) {
            float4 q = wq[lane * 16 + j];
            MATVEC4(q, j * 4, v, mxv)
        }
    }
    float mxn = fmaxf(sqrtf(wsum(mxv * mxv)), MINV);
    float res = tanhf(mxn / vn * artanhf_(vn)) * mxv / mxn;
    if (__ballot(mxv != 0.f) == 0ull) res = 0.f;   // all(mx==0) guard
    float rn = fmaxf(sqrtf(wsum(res * res)), MINV);
    if (rn > MAXNRM) res = res / rn * MAXNRM;

    float hb = sHb[lane];
    float h2 = sH2;
    float r2 = wsum(res * res), rh = wsum(res * hb);
    float o3 = ((1.f + 2.f * rh + h2) * res + (1.f - r2) * hb)
             / fmaxf(1.f + 2.f * rh + r2 * h2, MINV);
    float on = fmaxf(sqrtf(wsum(o3 * o3)), MINV);
    if (on > MAXNRM) o3 = o3 / on * MAXNRM;

    // ---- final: expmap0(tanh(logmap0(o3))) ----
    float on2 = fmaxf(sqrtf(wsum(o3 * o3)), MINV);
    float tl  = tanhf(artanhf_(on2) / on2 * o3);
    float tn  = fmaxf(sqrtf(wsum(tl * tl)), MINV);
    out[(size_t)b * 64 + lane] = tanhf(tn) * tl / tn;
}

extern "C" void kernel_launch(void* const* d_in, const int* in_sizes, int n_in,
                              void* d_out, int out_size, void* d_ws, size_t ws_size,
                              hipStream_t stream) {
    const float* self_v = (const float*)d_in[0];
    const float* user_v = (const float*)d_in[1];
    const float* ent_v  = (const float*)d_in[2];
    const float* item_e = (const float*)d_in[3];
    const float* Wr     = (const float*)d_in[4];
    const float* Wui    = (const float*)d_in[5];
    const float* linW   = (const float*)d_in[6];
    const float* linb   = (const float*)d_in[7];
    float* out = (float*)d_out;

    const int B = in_sizes[0] / 64;   // 2048

    // Kernel 1: one block per (b,s), parks SCALED logits in out[b*64+s] (s<16).
    // Kernel 2 consumes them and overwrites the full row. No workspace needed.
    logits_kernel<<<B * 16, 256, 0, stream>>>(self_v, ent_v, Wr, out);
    tail_kernel<<<B, 256, 0, stream>>>(self_v, user_v, ent_v, item_e,
                                       Wui, linW, linb, out);
}